// Round 1
// baseline (4092.572 us; speedup 1.0000x reference)
//
#include <hip/hip_runtime.h>
#include <math.h>

#define N_NODES 100000

struct alignas(16) f4 { float v[4]; };

// ---------------- degrees ----------------
__global__ __launch_bounds__(256) void k_degrees(const int* __restrict__ src,
                                                 const int* __restrict__ dst,
                                                 int E,
                                                 int* __restrict__ degs,
                                                 int* __restrict__ degd) {
    int i = blockIdx.x * 256 + threadIdx.x;
    if (i < E) {
        atomicAdd(&degs[src[i]], 1);
        atomicAdd(&degd[dst[i]], 1);
    }
}

__global__ __launch_bounds__(256) void k_norms(const int* __restrict__ degs,
                                               const int* __restrict__ degd,
                                               float* __restrict__ ns,
                                               float* __restrict__ nd,
                                               int n) {
    int i = blockIdx.x * 256 + threadIdx.x;
    if (i < n) {
        int a = degs[i];
        int b = degd[i];
        ns[i] = (a > 0) ? rsqrtf((float)a) : 0.0f;
        nd[i] = (b > 0) ? rsqrtf((float)b) : 0.0f;
    }
}

// ---------------- GEMM: C[n,OUT] = (A[n,K] @ W[K,OUT]) * ns[row] ----------------
// 64x64 tile per block (256 threads), 4x4 register tile per thread.
// W staged zero-padded to 64 cols in LDS; A tile staged in LDS with +4 pad.
template <int K, int OUT>
__global__ __launch_bounds__(256) void k_gemm_scale(const float* __restrict__ A,
                                                    const float* __restrict__ W,
                                                    const float* __restrict__ ns,
                                                    float* __restrict__ C,
                                                    int n) {
    constexpr int AS = K + 4; // padded A row stride in LDS
    __shared__ float Ws[K * 64];
    __shared__ float As[64 * AS];

    const int tid = threadIdx.x;
    const int r0 = blockIdx.x * 64;

    // stage W (zero-pad cols >= OUT)
    for (int i = tid; i < K * 64; i += 256) {
        int k = i >> 6;
        int c = i & 63;
        Ws[i] = (c < OUT) ? W[k * OUT + c] : 0.0f;
    }
    // stage A tile, coalesced float4, zero-fill rows >= n
    for (int i = tid * 4; i < 64 * K; i += 1024) {
        int r = i / K;
        int c = i - r * K;
        f4 v;
        if (r0 + r < n) {
            v = *(const f4*)&A[(size_t)(r0 + r) * K + c];
        } else {
            v.v[0] = v.v[1] = v.v[2] = v.v[3] = 0.0f;
        }
        *(f4*)&As[r * AS + c] = v;
    }
    __syncthreads();

    const int tr = tid >> 4;  // 0..15 -> rows tr*4 .. tr*4+3
    const int tc = tid & 15;  // 0..15 -> cols tc*4 .. tc*4+3

    float acc[4][4];
#pragma unroll
    for (int i = 0; i < 4; ++i)
#pragma unroll
        for (int j = 0; j < 4; ++j) acc[i][j] = 0.0f;

    for (int k = 0; k < K; k += 4) {
        f4 av[4], wv[4];
#pragma unroll
        for (int i = 0; i < 4; ++i)
            av[i] = *(const f4*)&As[(tr * 4 + i) * AS + k];
#pragma unroll
        for (int kk = 0; kk < 4; ++kk)
            wv[kk] = *(const f4*)&Ws[(k + kk) * 64 + tc * 4];
#pragma unroll
        for (int i = 0; i < 4; ++i)
#pragma unroll
            for (int j = 0; j < 4; ++j)
                acc[i][j] += av[i].v[0] * wv[0].v[j] + av[i].v[1] * wv[1].v[j] +
                             av[i].v[2] * wv[2].v[j] + av[i].v[3] * wv[3].v[j];
    }

    // store (scaled by ns[row]); col block tc*4..tc*4+3 is entirely in/out since OUT%4==0
    if (tc * 4 < OUT) {
#pragma unroll
        for (int i = 0; i < 4; ++i) {
            int row = r0 + tr * 4 + i;
            if (row < n) {
                float s = ns[row];
                f4 o;
#pragma unroll
                for (int j = 0; j < 4; ++j) o.v[j] = acc[i][j] * s;
                *(f4*)&C[(size_t)row * OUT + tc * 4] = o;
            }
        }
    }
}

// ---------------- SpMM: Agg[dst] += H[src], D = 64 ----------------
__global__ __launch_bounds__(256) void k_spmm64(const int* __restrict__ src,
                                                const int* __restrict__ dst,
                                                int E,
                                                const float* __restrict__ H,
                                                float* __restrict__ Agg) {
    int t = blockIdx.x * 256 + threadIdx.x;
    int e = t >> 4;
    int q = t & 15;
    if (e >= E) return;
    int s = src[e];
    int d = dst[e];
    f4 v = *(const f4*)&H[(size_t)s * 64 + q * 4];
    float* ap = &Agg[(size_t)d * 64 + q * 4];
    atomicAdd(ap + 0, v.v[0]);
    atomicAdd(ap + 1, v.v[1]);
    atomicAdd(ap + 2, v.v[2]);
    atomicAdd(ap + 3, v.v[3]);
}

// ---------------- SpMM: D = 40 (10 threads/edge, 4 floats each) ----------------
__global__ __launch_bounds__(256) void k_spmm40(const int* __restrict__ src,
                                                const int* __restrict__ dst,
                                                int E,
                                                const float* __restrict__ H,
                                                float* __restrict__ Agg) {
    int t = blockIdx.x * 256 + threadIdx.x;
    int e = t / 10;
    int q = t - e * 10;
    if (e >= E) return;
    int s = src[e];
    int d = dst[e];
    f4 v = *(const f4*)&H[(size_t)s * 40 + q * 4];
    float* ap = &Agg[(size_t)d * 40 + q * 4];
    atomicAdd(ap + 0, v.v[0]);
    atomicAdd(ap + 1, v.v[1]);
    atomicAdd(ap + 2, v.v[2]);
    atomicAdd(ap + 3, v.v[3]);
}

// ---------------- post: out = log_softmax(relu?(Agg*nd + b)) ----------------
// one 64-lane wave per node; lanes >= D masked.
template <int D, bool RELU>
__global__ __launch_bounds__(256) void k_post(const float* __restrict__ Agg,
                                              const float* __restrict__ nd,
                                              const float* __restrict__ b,
                                              float* __restrict__ Out,
                                              int n) {
    int node = blockIdx.x * 4 + (threadIdx.x >> 6);
    int lane = threadIdx.x & 63;
    if (node >= n) return;
    bool active = lane < D;
    float v = -INFINITY;
    if (active) {
        float x = Agg[(size_t)node * D + lane] * nd[node] + b[lane];
        if (RELU) x = fmaxf(x, 0.0f);
        v = x;
    }
    // wave max
    float m = v;
#pragma unroll
    for (int off = 32; off > 0; off >>= 1) m = fmaxf(m, __shfl_xor(m, off));
    float ex = active ? expf(v - m) : 0.0f;
    float ssum = ex;
#pragma unroll
    for (int off = 32; off > 0; off >>= 1) ssum += __shfl_xor(ssum, off);
    if (active) Out[(size_t)node * D + lane] = (v - m) - logf(ssum);
}

extern "C" void kernel_launch(void* const* d_in, const int* in_sizes, int n_in,
                              void* d_out, int out_size, void* d_ws, size_t ws_size,
                              hipStream_t stream) {
    const float* feats = (const float*)d_in[0];
    const int* src = (const int*)d_in[1];
    const int* dst = (const int*)d_in[2];
    const float* W0 = (const float*)d_in[3];
    const float* b0 = (const float*)d_in[4];
    const float* W1 = (const float*)d_in[5];
    const float* b1 = (const float*)d_in[6];
    const float* W2 = (const float*)d_in[7];
    const float* b2 = (const float*)d_in[8];
    float* out = (float*)d_out;

    const int N = N_NODES;
    const int E = in_sizes[1];

    // workspace layout
    float* ns = (float*)d_ws;              // N
    float* nd = ns + N;                    // N
    float* bufA = nd + N;                  // N*64  (gemm out / degS scratch)
    float* bufB = bufA + (size_t)N * 64;   // N*64  (agg / degD scratch)
    float* bufC = bufB + (size_t)N * 64;   // N*64  (post out)
    int* degS = (int*)bufA;
    int* degD = (int*)bufB;

    // 1) degrees + norms
    hipMemsetAsync(degS, 0, (size_t)N * sizeof(int), stream);
    hipMemsetAsync(degD, 0, (size_t)N * sizeof(int), stream);
    k_degrees<<<(E + 255) / 256, 256, 0, stream>>>(src, dst, E, degS, degD);
    k_norms<<<(N + 255) / 256, 256, 0, stream>>>(degS, degD, ns, nd, N);

    const int gemm_blocks = (N + 63) / 64;

    // ---- layer 0: feats[N,128] @ W0 -> 64, relu, log_softmax ----
    k_gemm_scale<128, 64><<<gemm_blocks, 256, 0, stream>>>(feats, W0, ns, bufA, N);
    hipMemsetAsync(bufB, 0, (size_t)N * 64 * sizeof(float), stream);
    k_spmm64<<<(E * 16 + 255) / 256, 256, 0, stream>>>(src, dst, E, bufA, bufB);
    k_post<64, true><<<(N + 3) / 4, 256, 0, stream>>>(bufB, nd, b0, bufC, N);

    // ---- layer 1: bufC[N,64] @ W1 -> 64, relu, log_softmax ----
    k_gemm_scale<64, 64><<<gemm_blocks, 256, 0, stream>>>(bufC, W1, ns, bufA, N);
    hipMemsetAsync(bufB, 0, (size_t)N * 64 * sizeof(float), stream);
    k_spmm64<<<(E * 16 + 255) / 256, 256, 0, stream>>>(src, dst, E, bufA, bufB);
    k_post<64, true><<<(N + 3) / 4, 256, 0, stream>>>(bufB, nd, b1, bufC, N);

    // ---- layer 2: bufC[N,64] @ W2 -> 40, log_softmax -> out ----
    k_gemm_scale<64, 40><<<gemm_blocks, 256, 0, stream>>>(bufC, W2, ns, bufA, N);
    hipMemsetAsync(bufB, 0, (size_t)N * 40 * sizeof(float), stream);
    k_spmm40<<<((long long)E * 10 + 255) / 256, 256, 0, stream>>>(src, dst, E, bufA, bufB);
    k_post<40, false><<<(N + 3) / 4, 256, 0, stream>>>(bufB, nd, b2, out, N);
}

// Round 2
// 660.889 us; speedup vs baseline: 6.1925x; 6.1925x over previous
//
#include <hip/hip_runtime.h>
#include <math.h>

#define N_NODES 100000
#define SCAN_CHUNK 2048

struct alignas(16) f4 { float v[4]; };

// ---------------- degrees ----------------
__global__ __launch_bounds__(256) void k_degrees(const int* __restrict__ src,
                                                 const int* __restrict__ dst,
                                                 int E,
                                                 int* __restrict__ degs,
                                                 int* __restrict__ degd) {
    int i = blockIdx.x * 256 + threadIdx.x;
    if (i < E) {
        atomicAdd(&degs[src[i]], 1);
        atomicAdd(&degd[dst[i]], 1);
    }
}

__global__ __launch_bounds__(256) void k_norms(const int* __restrict__ degs,
                                               const int* __restrict__ degd,
                                               float* __restrict__ ns,
                                               float* __restrict__ nd,
                                               int n) {
    int i = blockIdx.x * 256 + threadIdx.x;
    if (i < n) {
        int a = degs[i];
        int b = degd[i];
        ns[i] = (a > 0) ? rsqrtf((float)a) : 0.0f;
        nd[i] = (b > 0) ? rsqrtf((float)b) : 0.0f;
    }
}

// ---------------- exclusive scan of degd -> row_ptr (3 kernels) ----------------
__global__ __launch_bounds__(256) void k_block_sums(const int* __restrict__ deg, int n,
                                                    int* __restrict__ bsums) {
    __shared__ int sdata[256];
    int base = blockIdx.x * SCAN_CHUNK;
    int s = 0;
    for (int i = threadIdx.x; i < SCAN_CHUNK; i += 256) {
        int idx = base + i;
        s += (idx < n) ? deg[idx] : 0;
    }
    sdata[threadIdx.x] = s;
    __syncthreads();
    for (int off = 128; off > 0; off >>= 1) {
        if (threadIdx.x < off) sdata[threadIdx.x] += sdata[threadIdx.x + off];
        __syncthreads();
    }
    if (threadIdx.x == 0) bsums[blockIdx.x] = sdata[0];
}

__global__ void k_scan_bsums(int* __restrict__ bsums, int nb, int* __restrict__ row_ptr, int n) {
    if (threadIdx.x == 0 && blockIdx.x == 0) {
        int acc = 0;
        for (int i = 0; i < nb; ++i) {
            int v = bsums[i];
            bsums[i] = acc;
            acc += v;
        }
        row_ptr[n] = acc;
    }
}

__global__ __launch_bounds__(256) void k_scan_write(const int* __restrict__ deg, int n,
                                                    const int* __restrict__ bsums,
                                                    int* __restrict__ row_ptr,
                                                    int* __restrict__ cursor) {
    __shared__ int sdata[256];
    int tid = threadIdx.x;
    int tbase = blockIdx.x * SCAN_CHUNK + tid * 8;
    int v[8];
    int s = 0;
#pragma unroll
    for (int j = 0; j < 8; ++j) {
        int idx = tbase + j;
        v[j] = (idx < n) ? deg[idx] : 0;
        s += v[j];
    }
    sdata[tid] = s;
    __syncthreads();
    // Hillis-Steele inclusive scan over 256 thread sums
    for (int off = 1; off < 256; off <<= 1) {
        int t = (tid >= off) ? sdata[tid - off] : 0;
        __syncthreads();
        sdata[tid] += t;
        __syncthreads();
    }
    int excl = sdata[tid] - s + bsums[blockIdx.x];
#pragma unroll
    for (int j = 0; j < 8; ++j) {
        int idx = tbase + j;
        if (idx < n) {
            row_ptr[idx] = excl;
            cursor[idx] = excl;
        }
        excl += v[j];
    }
}

__global__ __launch_bounds__(256) void k_scatter(const int* __restrict__ src,
                                                 const int* __restrict__ dst,
                                                 int E,
                                                 int* __restrict__ cursor,
                                                 int* __restrict__ csr_src) {
    int i = blockIdx.x * 256 + threadIdx.x;
    if (i < E) {
        int d = dst[i];
        int pos = atomicAdd(&cursor[d], 1);
        csr_src[pos] = src[i];
    }
}

// ---------------- GEMM: C[n,OUT] = (A[n,K] @ W[K,OUT]) * ns[row] ----------------
template <int K, int OUT>
__global__ __launch_bounds__(256) void k_gemm_scale(const float* __restrict__ A,
                                                    const float* __restrict__ W,
                                                    const float* __restrict__ ns,
                                                    float* __restrict__ C,
                                                    int n) {
    constexpr int AS = K + 4;
    __shared__ float Ws[K * 64];
    __shared__ float As[64 * AS];

    const int tid = threadIdx.x;
    const int r0 = blockIdx.x * 64;

    for (int i = tid; i < K * 64; i += 256) {
        int k = i >> 6;
        int c = i & 63;
        Ws[i] = (c < OUT) ? W[k * OUT + c] : 0.0f;
    }
    for (int i = tid * 4; i < 64 * K; i += 1024) {
        int r = i / K;
        int c = i - r * K;
        f4 v;
        if (r0 + r < n) {
            v = *(const f4*)&A[(size_t)(r0 + r) * K + c];
        } else {
            v.v[0] = v.v[1] = v.v[2] = v.v[3] = 0.0f;
        }
        *(f4*)&As[r * AS + c] = v;
    }
    __syncthreads();

    const int tr = tid >> 4;
    const int tc = tid & 15;

    float acc[4][4];
#pragma unroll
    for (int i = 0; i < 4; ++i)
#pragma unroll
        for (int j = 0; j < 4; ++j) acc[i][j] = 0.0f;

    for (int k = 0; k < K; k += 4) {
        f4 av[4], wv[4];
#pragma unroll
        for (int i = 0; i < 4; ++i)
            av[i] = *(const f4*)&As[(tr * 4 + i) * AS + k];
#pragma unroll
        for (int kk = 0; kk < 4; ++kk)
            wv[kk] = *(const f4*)&Ws[(k + kk) * 64 + tc * 4];
#pragma unroll
        for (int i = 0; i < 4; ++i)
#pragma unroll
            for (int j = 0; j < 4; ++j)
                acc[i][j] += av[i].v[0] * wv[0].v[j] + av[i].v[1] * wv[1].v[j] +
                             av[i].v[2] * wv[2].v[j] + av[i].v[3] * wv[3].v[j];
    }

    if (tc * 4 < OUT) {
#pragma unroll
        for (int i = 0; i < 4; ++i) {
            int row = r0 + tr * 4 + i;
            if (row < n) {
                float s = ns[row];
                f4 o;
#pragma unroll
                for (int j = 0; j < 4; ++j) o.v[j] = acc[i][j] * s;
                *(f4*)&C[(size_t)row * OUT + tc * 4] = o;
            }
        }
    }
}

// ---------------- fused CSR aggregate + (*nd + b) + relu? + log_softmax ----------------
// one 64-lane wave per node. Gather H[src*D + lane]; inactive lanes (lane>=D)
// read harmlessly past row end (H buffer always has N*64 slack) and are masked
// out of the epilogue.
template <int D, bool RELU>
__global__ __launch_bounds__(256) void k_agg_post(const int* __restrict__ row_ptr,
                                                  const int* __restrict__ csr_src,
                                                  const float* __restrict__ H,
                                                  const float* __restrict__ nd,
                                                  const float* __restrict__ b,
                                                  float* __restrict__ Out,
                                                  int n) {
    int node = blockIdx.x * 4 + (threadIdx.x >> 6);
    int lane = threadIdx.x & 63;
    if (node >= n) return;

    int beg = row_ptr[node];
    int end = row_ptr[node + 1];

    float a0 = 0.f, a1 = 0.f, a2 = 0.f, a3 = 0.f;
    for (int i = beg; i < end; i += 64) {
        int cnt = min(64, end - i);
        int idx = (lane < cnt) ? csr_src[i + lane] : 0;
        int j = 0;
        for (; j + 4 <= cnt; j += 4) {
            int s0 = __shfl(idx, j);
            int s1 = __shfl(idx, j + 1);
            int s2 = __shfl(idx, j + 2);
            int s3 = __shfl(idx, j + 3);
            a0 += H[(size_t)s0 * D + lane];
            a1 += H[(size_t)s1 * D + lane];
            a2 += H[(size_t)s2 * D + lane];
            a3 += H[(size_t)s3 * D + lane];
        }
        for (; j < cnt; ++j) {
            int s = __shfl(idx, j);
            a0 += H[(size_t)s * D + lane];
        }
    }
    float acc = (a0 + a1) + (a2 + a3);

    bool active = lane < D;
    float x = -INFINITY;
    if (active) {
        x = acc * nd[node] + b[lane];
        if (RELU) x = fmaxf(x, 0.0f);
    }
    float m = x;
#pragma unroll
    for (int off = 32; off > 0; off >>= 1) m = fmaxf(m, __shfl_xor(m, off));
    float ex = active ? expf(x - m) : 0.0f;
    float ssum = ex;
#pragma unroll
    for (int off = 32; off > 0; off >>= 1) ssum += __shfl_xor(ssum, off);
    if (active) Out[(size_t)node * D + lane] = (x - m) - logf(ssum);
}

extern "C" void kernel_launch(void* const* d_in, const int* in_sizes, int n_in,
                              void* d_out, int out_size, void* d_ws, size_t ws_size,
                              hipStream_t stream) {
    const float* feats = (const float*)d_in[0];
    const int* src = (const int*)d_in[1];
    const int* dst = (const int*)d_in[2];
    const float* W0 = (const float*)d_in[3];
    const float* b0 = (const float*)d_in[4];
    const float* W1 = (const float*)d_in[5];
    const float* b1 = (const float*)d_in[6];
    const float* W2 = (const float*)d_in[7];
    const float* b2 = (const float*)d_in[8];
    float* out = (float*)d_out;

    const int N = N_NODES;
    const int E = in_sizes[1];
    const int NB = (N + SCAN_CHUNK - 1) / SCAN_CHUNK;

    // workspace layout (all within the ~77.6 MB proven available in round 1)
    float* ns = (float*)d_ws;                 // N
    float* nd = ns + N;                       // N
    float* H = nd + N;                        // N*64  (gemm out, agg input)
    float* G = H + (size_t)N * 64;            // N*64  (post out, next gemm in)
    int* row_ptr = (int*)(G + (size_t)N * 64);// N+1
    int* cursor = row_ptr + (N + 1);          // N    (also degD)
    int* csr_src = cursor + N;                // E
    int* degS = csr_src + E;                  // N
    int* degD = degS + N;                     // N
    int* bsums = degD + N;                    // NB+1

    // 1) degrees + norms
    hipMemsetAsync(degS, 0, (size_t)N * sizeof(int), stream);
    hipMemsetAsync(degD, 0, (size_t)N * sizeof(int), stream);
    k_degrees<<<(E + 255) / 256, 256, 0, stream>>>(src, dst, E, degS, degD);
    k_norms<<<(N + 255) / 256, 256, 0, stream>>>(degS, degD, ns, nd, N);

    // 2) CSR by dst: exclusive scan of degD -> row_ptr, then scatter
    k_block_sums<<<NB, 256, 0, stream>>>(degD, N, bsums);
    k_scan_bsums<<<1, 64, 0, stream>>>(bsums, NB, row_ptr, N);
    k_scan_write<<<NB, 256, 0, stream>>>(degD, N, bsums, row_ptr, cursor);
    k_scatter<<<(E + 255) / 256, 256, 0, stream>>>(src, dst, E, cursor, csr_src);

    const int gemm_blocks = (N + 63) / 64;
    const int agg_blocks = (N + 3) / 4;

    // ---- layer 0 ----
    k_gemm_scale<128, 64><<<gemm_blocks, 256, 0, stream>>>(feats, W0, ns, H, N);
    k_agg_post<64, true><<<agg_blocks, 256, 0, stream>>>(row_ptr, csr_src, H, nd, b0, G, N);

    // ---- layer 1 ----
    k_gemm_scale<64, 64><<<gemm_blocks, 256, 0, stream>>>(G, W1, ns, H, N);
    k_agg_post<64, true><<<agg_blocks, 256, 0, stream>>>(row_ptr, csr_src, H, nd, b1, G, N);

    // ---- layer 2 ----
    k_gemm_scale<64, 40><<<gemm_blocks, 256, 0, stream>>>(G, W2, ns, H, N);
    k_agg_post<40, false><<<agg_blocks, 256, 0, stream>>>(row_ptr, csr_src, H, nd, b2, out, N);
}

// Round 3
// 606.210 us; speedup vs baseline: 6.7511x; 1.0902x over previous
//
#include <hip/hip_runtime.h>
#include <math.h>

#define N_NODES 100000
#define SCAN_CHUNK 2048
#define NPASS 4

struct alignas(16) f4 { float v[4]; };
struct alignas(8) us4 { unsigned short v[4]; };

__device__ inline unsigned short f2bf(float x) {
    union { float f; unsigned int u; } v;
    v.f = x;
    unsigned int r = v.u + 0x7FFF + ((v.u >> 16) & 1);
    return (unsigned short)(r >> 16);
}

__device__ inline float bf2f(unsigned short h) {
    union { unsigned int u; float f; } v;
    v.u = ((unsigned int)h) << 16;
    return v.f;
}

// ---------------- degrees ----------------
__global__ __launch_bounds__(256) void k_degrees(const int* __restrict__ src,
                                                 const int* __restrict__ dst,
                                                 int E,
                                                 int* __restrict__ degs,
                                                 int* __restrict__ degd) {
    int i = blockIdx.x * 256 + threadIdx.x;
    if (i < E) {
        atomicAdd(&degs[src[i]], 1);
        atomicAdd(&degd[dst[i]], 1);
    }
}

// ---------------- exclusive scan of degd -> row_ptr (+ norms fused) ----------------
__global__ __launch_bounds__(256) void k_block_sums(const int* __restrict__ deg, int n,
                                                    int* __restrict__ bsums) {
    __shared__ int sdata[256];
    int base = blockIdx.x * SCAN_CHUNK;
    int s = 0;
    for (int i = threadIdx.x; i < SCAN_CHUNK; i += 256) {
        int idx = base + i;
        s += (idx < n) ? deg[idx] : 0;
    }
    sdata[threadIdx.x] = s;
    __syncthreads();
    for (int off = 128; off > 0; off >>= 1) {
        if (threadIdx.x < off) sdata[threadIdx.x] += sdata[threadIdx.x + off];
        __syncthreads();
    }
    if (threadIdx.x == 0) bsums[blockIdx.x] = sdata[0];
}

__global__ void k_scan_bsums(int* __restrict__ bsums, int nb, int* __restrict__ row_ptr, int n) {
    if (threadIdx.x == 0 && blockIdx.x == 0) {
        int acc = 0;
        for (int i = 0; i < nb; ++i) {
            int v = bsums[i];
            bsums[i] = acc;
            acc += v;
        }
        row_ptr[n] = acc;
    }
}

// scan-write row_ptr/cursor AND compute ns/nd (norms fused here)
__global__ __launch_bounds__(256) void k_scan_write(const int* __restrict__ degd,
                                                    const int* __restrict__ degs,
                                                    int n,
                                                    const int* __restrict__ bsums,
                                                    int* __restrict__ row_ptr,
                                                    int* __restrict__ cursor,
                                                    float* __restrict__ ns,
                                                    float* __restrict__ nd) {
    __shared__ int sdata[256];
    int tid = threadIdx.x;
    int tbase = blockIdx.x * SCAN_CHUNK + tid * 8;
    int v[8];
    int s = 0;
#pragma unroll
    for (int j = 0; j < 8; ++j) {
        int idx = tbase + j;
        v[j] = (idx < n) ? degd[idx] : 0;
        s += v[j];
    }
    sdata[tid] = s;
    __syncthreads();
    for (int off = 1; off < 256; off <<= 1) {
        int t = (tid >= off) ? sdata[tid - off] : 0;
        __syncthreads();
        sdata[tid] += t;
        __syncthreads();
    }
    int excl = sdata[tid] - s + bsums[blockIdx.x];
#pragma unroll
    for (int j = 0; j < 8; ++j) {
        int idx = tbase + j;
        if (idx < n) {
            row_ptr[idx] = excl;
            cursor[idx] = excl;
            int a = degs[idx];
            ns[idx] = (a > 0) ? rsqrtf((float)a) : 0.0f;
            nd[idx] = (v[j] > 0) ? rsqrtf((float)v[j]) : 0.0f;
        }
        excl += v[j];
    }
}

// range-partitioned scatter: only edges with dst in [lo,hi) — keeps the live
// csr_src write window ~1.6 MB so L2 merges same-line writes before eviction.
__global__ __launch_bounds__(256) void k_scatter_range(const int* __restrict__ src,
                                                       const int* __restrict__ dst,
                                                       int E,
                                                       int* __restrict__ cursor,
                                                       int* __restrict__ csr_src,
                                                       int lo, int hi) {
    int i = blockIdx.x * 256 + threadIdx.x;
    if (i < E) {
        int d = dst[i];
        if (d >= lo && d < hi) {
            int pos = atomicAdd(&cursor[d], 1);
            csr_src[pos] = src[i];
        }
    }
}

// ---------------- GEMM: C[n,OUT] = bf16((A[n,K] @ W[K,OUT]) * ns[row]) ----------------
template <int K, int OUT>
__global__ __launch_bounds__(256) void k_gemm_scale(const float* __restrict__ A,
                                                    const float* __restrict__ W,
                                                    const float* __restrict__ ns,
                                                    unsigned short* __restrict__ C,
                                                    int n) {
    constexpr int AS = K + 4;
    __shared__ float Ws[K * 64];
    __shared__ float As[64 * AS];

    const int tid = threadIdx.x;
    const int r0 = blockIdx.x * 64;

    for (int i = tid; i < K * 64; i += 256) {
        int k = i >> 6;
        int c = i & 63;
        Ws[i] = (c < OUT) ? W[k * OUT + c] : 0.0f;
    }
    for (int i = tid * 4; i < 64 * K; i += 1024) {
        int r = i / K;
        int c = i - r * K;
        f4 v;
        if (r0 + r < n) {
            v = *(const f4*)&A[(size_t)(r0 + r) * K + c];
        } else {
            v.v[0] = v.v[1] = v.v[2] = v.v[3] = 0.0f;
        }
        *(f4*)&As[r * AS + c] = v;
    }
    __syncthreads();

    const int tr = tid >> 4;
    const int tc = tid & 15;

    float acc[4][4];
#pragma unroll
    for (int i = 0; i < 4; ++i)
#pragma unroll
        for (int j = 0; j < 4; ++j) acc[i][j] = 0.0f;

    for (int k = 0; k < K; k += 4) {
        f4 av[4], wv[4];
#pragma unroll
        for (int i = 0; i < 4; ++i)
            av[i] = *(const f4*)&As[(tr * 4 + i) * AS + k];
#pragma unroll
        for (int kk = 0; kk < 4; ++kk)
            wv[kk] = *(const f4*)&Ws[(k + kk) * 64 + tc * 4];
#pragma unroll
        for (int i = 0; i < 4; ++i)
#pragma unroll
            for (int j = 0; j < 4; ++j)
                acc[i][j] += av[i].v[0] * wv[0].v[j] + av[i].v[1] * wv[1].v[j] +
                             av[i].v[2] * wv[2].v[j] + av[i].v[3] * wv[3].v[j];
    }

    if (tc * 4 < OUT) {
#pragma unroll
        for (int i = 0; i < 4; ++i) {
            int row = r0 + tr * 4 + i;
            if (row < n) {
                float s = ns[row];
                us4 o;
#pragma unroll
                for (int j = 0; j < 4; ++j) o.v[j] = f2bf(acc[i][j] * s);
                *(us4*)&C[(size_t)row * OUT + tc * 4] = o;
            }
        }
    }
}

// ---------------- fused CSR aggregate (bf16 gather) + (*nd + b) + relu? + log_softmax ----------------
template <int D, bool RELU>
__global__ __launch_bounds__(256) void k_agg_post(const int* __restrict__ row_ptr,
                                                  const int* __restrict__ csr_src,
                                                  const unsigned short* __restrict__ H,
                                                  const float* __restrict__ nd,
                                                  const float* __restrict__ b,
                                                  float* __restrict__ Out,
                                                  int n) {
    int node = blockIdx.x * 4 + (threadIdx.x >> 6);
    int lane = threadIdx.x & 63;
    if (node >= n) return;

    int beg = row_ptr[node];
    int end = row_ptr[node + 1];

    float a0 = 0.f, a1 = 0.f, a2 = 0.f, a3 = 0.f;
    for (int i = beg; i < end; i += 64) {
        int cnt = min(64, end - i);
        int idx = (lane < cnt) ? csr_src[i + lane] : 0;
        int j = 0;
        for (; j + 4 <= cnt; j += 4) {
            int s0 = __shfl(idx, j);
            int s1 = __shfl(idx, j + 1);
            int s2 = __shfl(idx, j + 2);
            int s3 = __shfl(idx, j + 3);
            a0 += bf2f(H[(size_t)s0 * D + lane]);
            a1 += bf2f(H[(size_t)s1 * D + lane]);
            a2 += bf2f(H[(size_t)s2 * D + lane]);
            a3 += bf2f(H[(size_t)s3 * D + lane]);
        }
        for (; j < cnt; ++j) {
            int s = __shfl(idx, j);
            a0 += bf2f(H[(size_t)s * D + lane]);
        }
    }
    float acc = (a0 + a1) + (a2 + a3);

    bool active = lane < D;
    float x = -INFINITY;
    if (active) {
        x = acc * nd[node] + b[lane];
        if (RELU) x = fmaxf(x, 0.0f);
    }
    float m = x;
#pragma unroll
    for (int off = 32; off > 0; off >>= 1) m = fmaxf(m, __shfl_xor(m, off));
    float ex = active ? expf(x - m) : 0.0f;
    float ssum = ex;
#pragma unroll
    for (int off = 32; off > 0; off >>= 1) ssum += __shfl_xor(ssum, off);
    if (active) Out[(size_t)node * D + lane] = (x - m) - logf(ssum);
}

extern "C" void kernel_launch(void* const* d_in, const int* in_sizes, int n_in,
                              void* d_out, int out_size, void* d_ws, size_t ws_size,
                              hipStream_t stream) {
    const float* feats = (const float*)d_in[0];
    const int* src = (const int*)d_in[1];
    const int* dst = (const int*)d_in[2];
    const float* W0 = (const float*)d_in[3];
    const float* b0 = (const float*)d_in[4];
    const float* W1 = (const float*)d_in[5];
    const float* b1 = (const float*)d_in[6];
    const float* W2 = (const float*)d_in[7];
    const float* b2 = (const float*)d_in[8];
    float* out = (float*)d_out;

    const int N = N_NODES;
    const int E = in_sizes[1];
    const int NB = (N + SCAN_CHUNK - 1) / SCAN_CHUNK;

    // workspace layout (~48 MB, well under proven capacity)
    float* ns = (float*)d_ws;                       // N
    float* nd = ns + N;                             // N
    unsigned short* Hb = (unsigned short*)(nd + N); // N*64 bf16 (all layers; slack for D=40 tail reads)
    float* G = (float*)(Hb + (size_t)N * 64);       // N*64 fp32 (post out, next gemm in)
    int* row_ptr = (int*)(G + (size_t)N * 64);      // N+1
    int* cursor = row_ptr + (N + 1);                // N
    int* csr_src = cursor + N;                      // E
    int* degS = csr_src + E;                        // N
    int* degD = degS + N;                           // N
    int* bsums = degD + N;                          // NB

    // 1) degrees
    hipMemsetAsync(degS, 0, (size_t)N * sizeof(int), stream);
    hipMemsetAsync(degD, 0, (size_t)N * sizeof(int), stream);
    k_degrees<<<(E + 255) / 256, 256, 0, stream>>>(src, dst, E, degS, degD);

    // 2) CSR by dst: scan degD -> row_ptr (+ norms fused), then range-partitioned scatter
    k_block_sums<<<NB, 256, 0, stream>>>(degD, N, bsums);
    k_scan_bsums<<<1, 64, 0, stream>>>(bsums, NB, row_ptr, N);
    k_scan_write<<<NB, 256, 0, stream>>>(degD, degS, N, bsums, row_ptr, cursor, ns, nd);
    {
        int range = (N + NPASS - 1) / NPASS;
        for (int p = 0; p < NPASS; ++p) {
            int lo = p * range;
            int hi = min(N, lo + range);
            k_scatter_range<<<(E + 255) / 256, 256, 0, stream>>>(src, dst, E, cursor, csr_src, lo, hi);
        }
    }

    const int gemm_blocks = (N + 63) / 64;
    const int agg_blocks = (N + 3) / 4;

    // ---- layer 0 ----
    k_gemm_scale<128, 64><<<gemm_blocks, 256, 0, stream>>>(feats, W0, ns, Hb, N);
    k_agg_post<64, true><<<agg_blocks, 256, 0, stream>>>(row_ptr, csr_src, Hb, nd, b0, G, N);

    // ---- layer 1 ----
    k_gemm_scale<64, 64><<<gemm_blocks, 256, 0, stream>>>(G, W1, ns, Hb, N);
    k_agg_post<64, true><<<agg_blocks, 256, 0, stream>>>(row_ptr, csr_src, Hb, nd, b1, G, N);

    // ---- layer 2 ----
    k_gemm_scale<64, 40><<<gemm_blocks, 256, 0, stream>>>(G, W2, ns, Hb, N);
    k_agg_post<40, false><<<agg_blocks, 256, 0, stream>>>(row_ptr, csr_src, Hb, nd, b2, out, N);
}